// Round 9
// baseline (196.408 us; speedup 1.0000x reference)
//
#include <hip/hip_runtime.h>
#include <stdint.h>

// Problem constants (from reference): B=2, S=4096, D_MODEL=1024, H=16, d_k=64
// RADIUS = ceil(sqrt(4*0.28*ln(1e6))*2) = 8, window = 9 (positions s-8..s)
constexpr int S_LEN = 4096;
constexpr int DM    = 1024;
constexpr int RAD   = 8;
constexpr float INV2T = 1.7857142857142858f; // 1/(2*0.28)

constexpr int BM = 128, BN = 128, BK = 64;

typedef _Float16 h8v  __attribute__((ext_vector_type(8)));   // 8 f16 (4 VGPRs) MFMA frag
typedef float  f32x4  __attribute__((ext_vector_type(4)));   // 16x16 accumulator
typedef float  f32x16 __attribute__((ext_vector_type(16)));  // 32x32 accumulator

// async global->LDS, 16B/lane. LDS dst is wave-uniform base + lane*16 (HW rule).
static __device__ __forceinline__ void gl_lds16(const void* gp, void* lp) {
  auto g = (const __attribute__((address_space(1))) void*)(uintptr_t)gp;
  auto l = (__attribute__((address_space(3))) void*)(uint32_t)(uintptr_t)lp;
  __builtin_amdgcn_global_load_lds(g, l, 16, 0, 0);
}

// ---------------- prep: x->fp16 cast + 4x W transpose-cast, one launch -------
__global__ __launch_bounds__(256) void sda_prep_kernel(
    const float* __restrict__ X, _Float16* __restrict__ XH,
    const float* __restrict__ W0, const float* __restrict__ W1,
    const float* __restrict__ W2, const float* __restrict__ W3,
    _Float16* __restrict__ T0, _Float16* __restrict__ T1,
    _Float16* __restrict__ T2, _Float16* __restrict__ T3) {
  __shared__ float t[32][33];
  int z = blockIdx.z;
  int tx = threadIdx.x, ty = threadIdx.y;
  if (z < 4) {
    const float* W = z == 0 ? W0 : (z == 1 ? W1 : (z == 2 ? W2 : W3));
    _Float16*    T = z == 0 ? T0 : (z == 1 ? T1 : (z == 2 ? T2 : T3));
    int n0 = blockIdx.x * 32, k0 = blockIdx.y * 32;
#pragma unroll
    for (int i = 0; i < 4; ++i)
      t[ty + 8 * i][tx] = W[(size_t)(k0 + ty + 8 * i) * DM + n0 + tx];
    __syncthreads();
#pragma unroll
    for (int i = 0; i < 4; ++i)
      T[(size_t)(n0 + ty + 8 * i) * DM + k0 + tx] = (_Float16)t[tx][ty + 8 * i];
  } else {
    int blk = (z - 4) * 1024 + blockIdx.y * 32 + blockIdx.x;
    int i = blk * 256 + ty * 32 + tx;
    const float4* x4 = (const float4*)X;
    float4 a = x4[2 * i], b = x4[2 * i + 1];
    float f[8] = {a.x, a.y, a.z, a.w, b.x, b.y, b.z, b.w};
    union { _Float16 h[8]; uint4 v; } o;
#pragma unroll
    for (int j = 0; j < 8; ++j) o.h[j] = (_Float16)f[j];
    ((uint4*)XH)[i] = o.v;
  }
}

// ------- fp16 GEMM, XCD-swizzled, BK=64, 32x32x16 MFMA -------
// Same verified staging (global_load_lds w16 + XOR chunk swizzle, conflicts=0)
// as R6-R8; inner loop switched 16x16x32 -> 32x32x16 (m119: 2495 vs 2176 TF,
// half the MFMA issue slots for the same ds_read count).
// Wave: 64x64 sub-tile = 2x2 tiles of 32x32. Per BK=64: 4 k16-steps x 4 MFMA.
// A/B frag: row = lane&31, k = (lane>>5)*8 + j (k-contiguous b128 from [row][k]).
// C/D (m74/m101): col = lane&31, row = (reg&3) + 8*(reg>>2) + 4*(lane>>5).
template <bool OUTF16>
__global__ __launch_bounds__(256) void sda_gemm32_kernel(
    const _Float16* __restrict__ A, const _Float16* __restrict__ Bt,
    void* __restrict__ C0, void* __restrict__ C1, void* __restrict__ C2) {
  constexpr int Kd = DM;
  __shared__ __align__(16) _Float16 As[BM * BK];  // 16 KB, 128B rows, chunk-XORed
  __shared__ __align__(16) _Float16 Bs[BN * BK];  // 16 KB

  int blk = blockIdx.x;
  int xcd = blk & 7, slot = blk >> 3;
  int xt = slot >> 3, ys = slot & 7;    // x-major within XCD
  int yt = (xcd << 3) | ys;             // y-stripe per XCD
  int m0 = yt * BM, n0 = xt * BN;

  int tid = threadIdx.x, wid = tid >> 6, lane = tid & 63;
  int srow = lane >> 3;
  int sgk = ((lane & 7) ^ (srow & 7)) * 8;    // XOR-permuted global k-chunk
  int wm = (wid >> 1) * 64, wn = (wid & 1) * 64;
  int fm = lane & 31, fh = lane >> 5;         // 32x32 frag row / k-half

  f32x16 acc[2][2] = {};

  for (int kt = 0; kt < Kd / BK; ++kt) {
    if (kt) __syncthreads();
    int kk = kt * BK;
    int r0 = wid * 32;
#pragma unroll
    for (int i = 0; i < 4; ++i) {
      gl_lds16(A  + (size_t)(m0 + r0 + i * 8 + srow) * Kd + kk + sgk, &As[(r0 + i * 8) * BK]);
      gl_lds16(Bt + (size_t)(n0 + r0 + i * 8 + srow) * Kd + kk + sgk, &Bs[(r0 + i * 8) * BK]);
    }
    __syncthreads();

#pragma unroll
    for (int ks = 0; ks < 4; ++ks) {          // four k=16 steps per BK=64 tile
      int cbase = ks * 2 + fh;                // logical 8-f16 chunk index
      h8v af[2], bfr[2];
#pragma unroll
      for (int i = 0; i < 2; ++i) {
        int row = wm + i * 32 + fm;
        af[i] = *(const h8v*)&As[row * BK + ((cbase ^ (row & 7)) * 8)];
      }
#pragma unroll
      for (int j = 0; j < 2; ++j) {
        int row = wn + j * 32 + fm;
        bfr[j] = *(const h8v*)&Bs[row * BK + ((cbase ^ (row & 7)) * 8)];
      }
#pragma unroll
      for (int i = 0; i < 2; ++i)
#pragma unroll
        for (int j = 0; j < 2; ++j)
          acc[i][j] = __builtin_amdgcn_mfma_f32_32x32x16_f16(af[i], bfr[j], acc[i][j], 0, 0, 0);
    }
  }

  // Output select: which 1024-wide matrix this n-tile belongs to (QKV fusion).
  int which = n0 >> 10, nc = n0 & 1023;
  void* Cv = which == 0 ? C0 : (which == 1 ? C1 : C2);

  // 32x32 C/D: col = lane&31, row = (reg&3) + 8*(reg>>2) + 4*(lane>>5)
  int cc = lane & 31, rbase = 4 * fh;
#pragma unroll
  for (int i = 0; i < 2; ++i)
#pragma unroll
    for (int j = 0; j < 2; ++j) {
#pragma unroll
      for (int reg = 0; reg < 16; ++reg) {
        int row = (reg & 3) + 8 * (reg >> 2) + rbase;
        size_t o = (size_t)(m0 + wm + i * 32 + row) * DM + (nc + wn + j * 32 + cc);
        float v = acc[i][j][reg];
        if constexpr (OUTF16) ((_Float16*)Cv)[o] = (_Float16)v;
        else                  ((float*)Cv)[o] = v;
      }
    }
}

// ---------------- BARRIER-FREE per-wave windowed attention (R8-verified) -----
__global__ __launch_bounds__(256) void sda_attn_kernel(
    const _Float16* __restrict__ Q, const _Float16* __restrict__ K,
    const _Float16* __restrict__ V, _Float16* __restrict__ O) {
  constexpr int KS  = 72;  // kw row stride f16: 144B
  constexpr int VTS = 40;  // vt row stride f16: 80B
  constexpr int WS  = 40;  // wt row stride f16
  __shared__ __align__(16) _Float16 kw[4][32 * KS];
  __shared__ __align__(16) _Float16 vt[4][64 * VTS];
  __shared__ __align__(16) float    sc[4][16 * 33];
  __shared__ __align__(16) _Float16 wt[4][16 * WS];

  int bh = blockIdx.y, b = bh >> 4, h = bh & 15;
  int s0 = blockIdx.x * 64;
  int tid = threadIdx.x, wid = tid >> 6, lane = tid & 63;
  size_t headoff = (size_t)b * S_LEN * DM + h * 64;

  _Float16* kwp = kw[wid];
  _Float16* vtp = vt[wid];
  float*    scp = sc[wid];
  _Float16* wtp = wt[wid];

  int p0 = s0 + wid * 16 - RAD;
  int fm = lane & 15, fkg = (lane >> 4) * 8;
  int rr = (lane >> 4) * 4, cc = lane & 15;

  {
    uint4 z = make_uint4(0, 0, 0, 0);
    ((uint4*)wtp)[lane] = z;
    if (lane < 16) ((uint4*)wtp)[64 + lane] = z;
    *(uint4*)&vtp[lane * VTS + 24] = z;
  }

#pragma unroll
  for (int i = 0; i < 3; ++i) {
    int item = i * 64 + lane;
    int row = item >> 3, ch = (item & 7) * 8;
    int pos = p0 + row;
    uint4 kv = make_uint4(0, 0, 0, 0);
    if (pos >= 0) kv = *(const uint4*)(K + headoff + (size_t)pos * DM + ch);
    *(uint4*)&kwp[row * KS + ch] = kv;
  }
#pragma unroll
  for (int i = 0; i < 3; ++i) {
    int item = i * 64 + lane;
    int row = item >> 3, chb = (item & 7) * 8;
    int pos = p0 + row;
    uint4 vv = make_uint4(0, 0, 0, 0);
    if (pos >= 0) vv = *(const uint4*)(V + headoff + (size_t)pos * DM + chb);
    union { uint4 v; _Float16 hh[8]; } u; u.v = vv;
#pragma unroll
    for (int d = 0; d < 8; ++d) vtp[(chb + d) * VTS + row] = u.hh[d];
  }

  const _Float16* qrow = Q + headoff + (size_t)(s0 + wid * 16 + fm) * DM;
  h8v aq0 = *(const h8v*)(qrow + fkg);
  h8v aq1 = *(const h8v*)(qrow + 32 + fkg);

  f32x4 accs[2] = {};
#pragma unroll
  for (int t = 0; t < 2; ++t) {
    h8v bk0 = *(const h8v*)&kwp[(t * 16 + fm) * KS + fkg];
    h8v bk1 = *(const h8v*)&kwp[(t * 16 + fm) * KS + 32 + fkg];
    accs[t] = __builtin_amdgcn_mfma_f32_16x16x32_f16(aq0, bk0, accs[t], 0, 0, 0);
    accs[t] = __builtin_amdgcn_mfma_f32_16x16x32_f16(aq1, bk1, accs[t], 0, 0, 0);
  }
#pragma unroll
  for (int t = 0; t < 2; ++t)
#pragma unroll
    for (int r = 0; r < 4; ++r)
      scp[(rr + r) * 33 + t * 16 + cc] = accs[t][r];

  if (lane < 16) {
    int r = lane, s = s0 + wid * 16 + r;
    const float* my = &scp[r * 33 + r];
    float e[9], mx = -1e30f;
#pragma unroll
    for (int j = 0; j < 9; ++j) {
      float p = my[j] * INV2T;
      e[j] = (s - RAD + j >= 0) ? p : -1e30f;
      mx = fmaxf(mx, e[j]);
    }
    float se = 0.f;
#pragma unroll
    for (int j = 0; j < 9; ++j) { e[j] = __expf(e[j] - mx); se += e[j]; }
    float inv = 1.f / se;
#pragma unroll
    for (int j = 0; j < 9; ++j)
      wtp[r * WS + r + j] = (_Float16)(e[j] * inv);
  }

  f32x4 acco[4] = {};
  h8v aw = *(const h8v*)&wtp[fm * WS + fkg];
#pragma unroll
  for (int t = 0; t < 4; ++t) {
    h8v bv = *(const h8v*)&vtp[(t * 16 + fm) * VTS + fkg];
    acco[t] = __builtin_amdgcn_mfma_f32_16x16x32_f16(aw, bv, acco[t], 0, 0, 0);
  }
#pragma unroll
  for (int t = 0; t < 4; ++t)
#pragma unroll
    for (int r = 0; r < 4; ++r)
      O[headoff + (size_t)(s0 + wid * 16 + rr + r) * DM + t * 16 + cc] =
          (_Float16)acco[t][r];
}

extern "C" void kernel_launch(void* const* d_in, const int* in_sizes, int n_in,
                              void* d_out, int out_size, void* d_ws, size_t ws_size,
                              hipStream_t stream) {
  (void)in_sizes; (void)n_in; (void)out_size; (void)ws_size;
  const float* x  = (const float*)d_in[0];
  const float* Wq = (const float*)d_in[1];
  const float* Wk = (const float*)d_in[2];
  const float* Wv = (const float*)d_in[3];
  const float* Wo = (const float*)d_in[4];

  char* ws = (char*)d_ws;
  const size_t MB = 1ull << 20;
  _Float16* xh    = (_Float16*)(ws + 0);        // 16 MB
  _Float16* WqkvT = (_Float16*)(ws + 16 * MB);  // 6 MB: Wq^T|Wk^T|Wv^T
  _Float16* WoT   = (_Float16*)(ws + 22 * MB);  // 2 MB
  _Float16* Qh    = (_Float16*)(ws + 24 * MB);  // 16 MB each
  _Float16* Kh    = (_Float16*)(ws + 40 * MB);
  _Float16* Vh    = (_Float16*)(ws + 56 * MB);
  _Float16* Ah    = (_Float16*)(ws + 72 * MB);  // total 88 MB

  sda_prep_kernel<<<dim3(32, 32, 8), dim3(32, 8), 0, stream>>>(
      x, xh, Wq, Wk, Wv, Wo,
      WqkvT, WqkvT + (size_t)DM * DM, WqkvT + 2ull * DM * DM, WoT);

  // QKV fused: M=8192, N=3072 -> 1536 blocks (1D, XCD-swizzled)
  sda_gemm32_kernel<true><<<1536, 256, 0, stream>>>(xh, WqkvT, Qh, Kh, Vh);
  sda_attn_kernel<<<dim3(64, 32), 256, 0, stream>>>(Qh, Kh, Vh, Ah);
  // Wo: 128x128 -> 512 blocks
  sda_gemm32_kernel<false><<<512, 256, 0, stream>>>(Ah, WoT, d_out, d_out, d_out);
}

// Round 10
// 188.391 us; speedup vs baseline: 1.0426x; 1.0426x over previous
//
#include <hip/hip_runtime.h>
#include <stdint.h>

// Problem constants (from reference): B=2, S=4096, D_MODEL=1024, H=16, d_k=64
// RADIUS = ceil(sqrt(4*0.28*ln(1e6))*2) = 8, window = 9 (positions s-8..s)
constexpr int S_LEN = 4096;
constexpr int DM    = 1024;
constexpr int RAD   = 8;
constexpr float INV2T = 1.7857142857142858f; // 1/(2*0.28)

constexpr int BM = 128, BN = 128, BK = 64;   // BK=64: 32 MFMA/barrier (R6: 31.5->38% MfmaUtil)

typedef _Float16 h8v __attribute__((ext_vector_type(8)));  // 8 f16 (4 VGPRs) MFMA frag
typedef float f32x4  __attribute__((ext_vector_type(4)));  // MFMA accumulator

// async global->LDS, 16B/lane. LDS dst is wave-uniform base + lane*16 (HW rule).
static __device__ __forceinline__ void gl_lds16(const void* gp, void* lp) {
  auto g = (const __attribute__((address_space(1))) void*)(uintptr_t)gp;
  auto l = (__attribute__((address_space(3))) void*)(uint32_t)(uintptr_t)lp;
  __builtin_amdgcn_global_load_lds(g, l, 16, 0, 0);
}

// ---------------- prep: x->fp16 cast + 4x W transpose-cast, one launch -------
__global__ __launch_bounds__(256) void sda_prep_kernel(
    const float* __restrict__ X, _Float16* __restrict__ XH,
    const float* __restrict__ W0, const float* __restrict__ W1,
    const float* __restrict__ W2, const float* __restrict__ W3,
    _Float16* __restrict__ T0, _Float16* __restrict__ T1,
    _Float16* __restrict__ T2, _Float16* __restrict__ T3) {
  __shared__ float t[32][33];
  int z = blockIdx.z;
  int tx = threadIdx.x, ty = threadIdx.y;
  if (z < 4) {
    const float* W = z == 0 ? W0 : (z == 1 ? W1 : (z == 2 ? W2 : W3));
    _Float16*    T = z == 0 ? T0 : (z == 1 ? T1 : (z == 2 ? T2 : T3));
    int n0 = blockIdx.x * 32, k0 = blockIdx.y * 32;
#pragma unroll
    for (int i = 0; i < 4; ++i)
      t[ty + 8 * i][tx] = W[(size_t)(k0 + ty + 8 * i) * DM + n0 + tx];
    __syncthreads();
#pragma unroll
    for (int i = 0; i < 4; ++i)
      T[(size_t)(n0 + ty + 8 * i) * DM + k0 + tx] = (_Float16)t[tx][ty + 8 * i];
  } else {
    int blk = (z - 4) * 1024 + blockIdx.y * 32 + blockIdx.x;
    int i = blk * 256 + ty * 32 + tx;
    const float4* x4 = (const float4*)X;
    float4 a = x4[2 * i], b = x4[2 * i + 1];
    float f[8] = {a.x, a.y, a.z, a.w, b.x, b.y, b.z, b.w};
    union { _Float16 h[8]; uint4 v; } o;
#pragma unroll
    for (int j = 0; j < 8; ++j) o.h[j] = (_Float16)f[j];
    ((uint4*)XH)[i] = o.v;
  }
}

// ------- fp16 GEMM, XCD-swizzled, BK=64, 16x16x32 MFMA -------
// R8-verified state: MfmaUtil 38%, SQ_LDS_BANK_CONFLICT = 0, 57 us @ QKV.
// (R9's 32x32x16 variant REVERTED: it reintroduced 6.29e6 conflicts and
// regressed 57->64 us — the 32-row fragment geometry defeats the XOR swizzle.)
__global__ __launch_bounds__(256) void sda_gemm_qkv_kernel(
    const _Float16* __restrict__ A, const _Float16* __restrict__ Bt,
    _Float16* __restrict__ C0, _Float16* __restrict__ C1,
    _Float16* __restrict__ C2) {
  constexpr int Kd = DM;
  __shared__ __align__(16) _Float16 As[BM * BK];  // 16 KB, 128B rows, chunk-XORed
  __shared__ __align__(16) _Float16 Bs[BN * BK];  // 16 KB

  int blk = blockIdx.x;
  int xcd = blk & 7, slot = blk >> 3;
  int xt = slot >> 3, ys = slot & 7;    // x-major within XCD
  int yt = (xcd << 3) | ys;             // y-stripe per XCD
  int m0 = yt * BM, n0 = xt * BN;

  int tid = threadIdx.x, wid = tid >> 6, lane = tid & 63;
  int srow = lane >> 3;
  int sgk = ((lane & 7) ^ (srow & 7)) * 8;    // XOR-permuted global k-chunk
  int wm = (wid >> 1) * 64, wn = (wid & 1) * 64;
  int fm = lane & 15, fc = lane >> 4;

  f32x4 acc[4][4] = {};

  for (int kt = 0; kt < Kd / BK; ++kt) {
    if (kt) __syncthreads();
    int kk = kt * BK;
    int r0 = wid * 32;
#pragma unroll
    for (int i = 0; i < 4; ++i) {
      gl_lds16(A  + (size_t)(m0 + r0 + i * 8 + srow) * Kd + kk + sgk, &As[(r0 + i * 8) * BK]);
      gl_lds16(Bt + (size_t)(n0 + r0 + i * 8 + srow) * Kd + kk + sgk, &Bs[(r0 + i * 8) * BK]);
    }
    __syncthreads();

#pragma unroll
    for (int ks = 0; ks < 2; ++ks) {
      h8v af[4], bfr[4];
#pragma unroll
      for (int i = 0; i < 4; ++i) {
        int row = wm + i * 16 + fm;
        af[i] = *(const h8v*)&As[row * BK + (((ks * 4 + fc) ^ (row & 7)) * 8)];
      }
#pragma unroll
      for (int j = 0; j < 4; ++j) {
        int row = wn + j * 16 + fm;
        bfr[j] = *(const h8v*)&Bs[row * BK + (((ks * 4 + fc) ^ (row & 7)) * 8)];
      }
#pragma unroll
      for (int i = 0; i < 4; ++i)
#pragma unroll
        for (int j = 0; j < 4; ++j)
          acc[i][j] = __builtin_amdgcn_mfma_f32_16x16x32_f16(af[i], bfr[j], acc[i][j], 0, 0, 0);
    }
  }

  int which = n0 >> 10, nc = n0 & 1023;
  _Float16* Cv = which == 0 ? C0 : (which == 1 ? C1 : C2);

  int rr = (lane >> 4) * 4, cc = lane & 15;
#pragma unroll
  for (int i = 0; i < 4; ++i)
#pragma unroll
    for (int j = 0; j < 4; ++j) {
      size_t base = (size_t)(m0 + wm + i * 16 + rr) * DM + (nc + wn + j * 16 + cc);
#pragma unroll
      for (int r = 0; r < 4; ++r)
        Cv[base + (size_t)r * DM] = (_Float16)acc[i][j][r];
    }
}

// ------- Wo GEMM: 128x128, 16x16x32 (R8-verified), fp32 output ----
__global__ __launch_bounds__(256) void sda_gemm_wo_kernel(
    const _Float16* __restrict__ A, const _Float16* __restrict__ Bt,
    float* __restrict__ C) {
  constexpr int Kd = DM;
  __shared__ __align__(16) _Float16 As[BM * BK];
  __shared__ __align__(16) _Float16 Bs[BN * BK];

  int blk = blockIdx.x;
  int xcd = blk & 7, slot = blk >> 3;   // 64 slots/XCD
  int xt = slot >> 3, ys = slot & 7;    // 8 x-tiles, x-major
  int yt = (xcd << 3) | ys;
  int m0 = yt * BM, n0 = xt * BN;

  int tid = threadIdx.x, wid = tid >> 6, lane = tid & 63;
  int srow = lane >> 3;
  int sgk = ((lane & 7) ^ (srow & 7)) * 8;
  int wm = (wid >> 1) * 64, wn = (wid & 1) * 64;
  int fm = lane & 15, fc = lane >> 4;

  f32x4 acc[4][4] = {};

  for (int kt = 0; kt < Kd / BK; ++kt) {
    if (kt) __syncthreads();
    int kk = kt * BK;
    int r0 = wid * 32;
#pragma unroll
    for (int i = 0; i < 4; ++i) {
      gl_lds16(A  + (size_t)(m0 + r0 + i * 8 + srow) * Kd + kk + sgk, &As[(r0 + i * 8) * BK]);
      gl_lds16(Bt + (size_t)(n0 + r0 + i * 8 + srow) * Kd + kk + sgk, &Bs[(r0 + i * 8) * BK]);
    }
    __syncthreads();

#pragma unroll
    for (int ks = 0; ks < 2; ++ks) {
      h8v af[4], bfr[4];
#pragma unroll
      for (int i = 0; i < 4; ++i) {
        int row = wm + i * 16 + fm;
        af[i] = *(const h8v*)&As[row * BK + (((ks * 4 + fc) ^ (row & 7)) * 8)];
      }
#pragma unroll
      for (int j = 0; j < 4; ++j) {
        int row = wn + j * 16 + fm;
        bfr[j] = *(const h8v*)&Bs[row * BK + (((ks * 4 + fc) ^ (row & 7)) * 8)];
      }
#pragma unroll
      for (int i = 0; i < 4; ++i)
#pragma unroll
        for (int j = 0; j < 4; ++j)
          acc[i][j] = __builtin_amdgcn_mfma_f32_16x16x32_f16(af[i], bfr[j], acc[i][j], 0, 0, 0);
    }
  }

  int rr = (lane >> 4) * 4, cc = lane & 15;
#pragma unroll
  for (int i = 0; i < 4; ++i)
#pragma unroll
    for (int j = 0; j < 4; ++j) {
      size_t base = (size_t)(m0 + wm + i * 16 + rr) * DM + (n0 + wn + j * 16 + cc);
#pragma unroll
      for (int r = 0; r < 4; ++r)
        C[base + (size_t)r * DM] = acc[i][j][r];
    }
}

// ---------------- BARRIER-FREE per-wave windowed attention ----------------
// R8 structure minus the K LDS round-trip: QK B-fragments (K rows p0+t*16+fm,
// k-contiguous) load DIRECTLY from global. Validity is enforced by the score
// mask (-1e30 before max/exp), so out-of-band rows (pos<0, only near s=0) may
// read adjacent ws buffers: mapped, finite fp16 — never NaN. V keeps its LDS
// transpose (B-operand needs [dim][key]); its pos<0 select is dropped for the
// same reason (masked weights are exactly 0; 0 x finite = 0). vt key-cols
// 24..31 stay zeroed against stale-LDS NaN (0 x NaN != 0).
// LDS: 34.5 KB (was 52.5) -> more blocks/CU.
__global__ __launch_bounds__(256) void sda_attn_kernel(
    const _Float16* __restrict__ Q, const _Float16* __restrict__ K,
    const _Float16* __restrict__ V, _Float16* __restrict__ O) {
  constexpr int VTS = 40;  // vt row stride f16: 80B = 20 dw -> <=2-way (free)
  constexpr int WS  = 40;  // wt row stride f16
  __shared__ __align__(16) _Float16 vt[4][64 * VTS];  // 5 KB/wave [dim][key]
  __shared__ __align__(16) float    sc[4][16 * 33];   // 2.06 KB/wave
  __shared__ __align__(16) _Float16 wt[4][16 * WS];   // 1.25 KB/wave

  int bh = blockIdx.y, b = bh >> 4, h = bh & 15;
  int s0 = blockIdx.x * 64;
  int tid = threadIdx.x, wid = tid >> 6, lane = tid & 63;
  size_t headoff = (size_t)b * S_LEN * DM + h * 64;

  _Float16* vtp = vt[wid];
  float*    scp = sc[wid];
  _Float16* wtp = wt[wid];

  int p0 = s0 + wid * 16 - RAD;    // first key pos of this wave's 24-key band
  int fm = lane & 15, fkg = (lane >> 4) * 8;
  int rr = (lane >> 4) * 4, cc = lane & 15;

  // zero wt fully (80 x 16B) and vt key-cols 24..31 (stale-LDS NaN guard)
  {
    uint4 z = make_uint4(0, 0, 0, 0);
    ((uint4*)wtp)[lane] = z;
    if (lane < 16) ((uint4*)wtp)[64 + lane] = z;
    *(uint4*)&vtp[lane * VTS + 24] = z;
  }

  // stage V transposed: vt[dim][key], unconditional loads (see header note)
#pragma unroll
  for (int i = 0; i < 3; ++i) {
    int item = i * 64 + lane;
    int row = item >> 3, chb = (item & 7) * 8;
    uint4 vv = *(const uint4*)(V + headoff + (ptrdiff_t)(p0 + row) * DM + chb);
    union { uint4 v; _Float16 hh[8]; } u; u.v = vv;
#pragma unroll
    for (int d = 0; d < 8; ++d) vtp[(chb + d) * VTS + row] = u.hh[d];
  }

  // Q fragments straight from global (rows always valid)
  const _Float16* qrow = Q + headoff + (size_t)(s0 + wid * 16 + fm) * DM;
  h8v aq0 = *(const h8v*)(qrow + fkg);
  h8v aq1 = *(const h8v*)(qrow + 32 + fkg);

  // ---- QK^T: 2 key-tiles x K=64, K fragments direct from global ----
  f32x4 accs[2] = {};
#pragma unroll
  for (int t = 0; t < 2; ++t) {
    const _Float16* krow = K + headoff + (ptrdiff_t)(p0 + t * 16 + fm) * DM;
    h8v bk0 = *(const h8v*)(krow + fkg);
    h8v bk1 = *(const h8v*)(krow + 32 + fkg);
    accs[t] = __builtin_amdgcn_mfma_f32_16x16x32_f16(aq0, bk0, accs[t], 0, 0, 0);
    accs[t] = __builtin_amdgcn_mfma_f32_16x16x32_f16(aq1, bk1, accs[t], 0, 0, 0);
  }
#pragma unroll
  for (int t = 0; t < 2; ++t)
#pragma unroll
    for (int r = 0; r < 4; ++r)
      scp[(rr + r) * 33 + t * 16 + cc] = accs[t][r];

  // ---- softmax: lane r (0..15) owns q-row r; band cols r..r+8 (< 24) ----
  if (lane < 16) {
    int r = lane, s = s0 + wid * 16 + r;
    const float* my = &scp[r * 33 + r];
    float e[9], mx = -1e30f;
#pragma unroll
    for (int j = 0; j < 9; ++j) {
      float p = my[j] * INV2T;
      e[j] = (s - RAD + j >= 0) ? p : -1e30f;   // garbage cols are masked HERE
      mx = fmaxf(mx, e[j]);
    }
    float se = 0.f;
#pragma unroll
    for (int j = 0; j < 9; ++j) { e[j] = __expf(e[j] - mx); se += e[j]; }
    float inv = 1.f / se;
#pragma unroll
    for (int j = 0; j < 9; ++j)
      wtp[r * WS + r + j] = (_Float16)(e[j] * inv);
  }

  // ---- PV: O(16x64) = wt(16x32) @ V(32x64); one K=32 MFMA per n-tile ----
  f32x4 acco[4] = {};
  h8v aw = *(const h8v*)&wtp[fm * WS + fkg];
#pragma unroll
  for (int t = 0; t < 4; ++t) {
    h8v bv = *(const h8v*)&vtp[(t * 16 + fm) * VTS + fkg];
    acco[t] = __builtin_amdgcn_mfma_f32_16x16x32_f16(aw, bv, acco[t], 0, 0, 0);
  }
#pragma unroll
  for (int t = 0; t < 4; ++t)
#pragma unroll
    for (int r = 0; r < 4; ++r)
      O[headoff + (size_t)(s0 + wid * 16 + rr + r) * DM + t * 16 + cc] =
          (_Float16)acco[t][r];
}

extern "C" void kernel_launch(void* const* d_in, const int* in_sizes, int n_in,
                              void* d_out, int out_size, void* d_ws, size_t ws_size,
                              hipStream_t stream) {
  (void)in_sizes; (void)n_in; (void)out_size; (void)ws_size;
  const float* x  = (const float*)d_in[0];
  const float* Wq = (const float*)d_in[1];
  const float* Wk = (const float*)d_in[2];
  const float* Wv = (const float*)d_in[3];
  const float* Wo = (const float*)d_in[4];

  char* ws = (char*)d_ws;
  const size_t MB = 1ull << 20;
  _Float16* xh    = (_Float16*)(ws + 0);        // 16 MB
  _Float16* WqkvT = (_Float16*)(ws + 16 * MB);  // 6 MB: Wq^T|Wk^T|Wv^T
  _Float16* WoT   = (_Float16*)(ws + 22 * MB);  // 2 MB
  _Float16* Qh    = (_Float16*)(ws + 24 * MB);  // 16 MB each
  _Float16* Kh    = (_Float16*)(ws + 40 * MB);
  _Float16* Vh    = (_Float16*)(ws + 56 * MB);
  _Float16* Ah    = (_Float16*)(ws + 72 * MB);  // total 88 MB

  sda_prep_kernel<<<dim3(32, 32, 8), dim3(32, 8), 0, stream>>>(
      x, xh, Wq, Wk, Wv, Wo,
      WqkvT, WqkvT + (size_t)DM * DM, WqkvT + 2ull * DM * DM, WoT);

  // QKV fused: M=8192, N=3072 -> 1536 blocks (1D, XCD-swizzled)
  sda_gemm_qkv_kernel<<<1536, 256, 0, stream>>>(xh, WqkvT, Qh, Kh, Vh);
  sda_attn_kernel<<<dim3(64, 32), 256, 0, stream>>>(Qh, Kh, Vh, Ah);
  // Wo: 128x128 -> 512 blocks
  sda_gemm_wo_kernel<<<512, 256, 0, stream>>>(Ah, WoT, (float*)d_out);
}